// Round 1
// 344.577 us; speedup vs baseline: 1.0100x; 1.0100x over previous
//
#include <hip/hip_runtime.h>
#include <stdint.h>

#define N_NODES 50000
#define N_EDGES 1600000
#define F_IN    264
#define F_HID   48
#define F_CAT   144
#define F_MID   64
#define K_PAD   288   // 264 padded up to multiple of 32
#define K_MLP   160   // 144 padded up to multiple of 32
#define R_CNT   16    // count-array replication factor (atomic contention fix)

typedef unsigned short u16;
typedef unsigned int   u32;

using short8  = __attribute__((ext_vector_type(8))) short;
using floatx4 = __attribute__((ext_vector_type(4))) float;

__device__ __forceinline__ float bf2f(u16 u) {
    return __uint_as_float(((u32)u) << 16);
}
__device__ __forceinline__ u16 f2bf(float f) {
    u32 u = __float_as_uint(f);
    u32 r = (u + 0x7fffu + ((u >> 16) & 1u)) >> 16;   // round-nearest-even
    return (u16)r;
}
// dtype-agnostic scalar float load: isbf ? bf16[i] : f32[i]
__device__ __forceinline__ float ldf(const void* p, size_t i, int isbf) {
    return isbf ? bf2f(((const u16*)p)[i]) : ((const float*)p)[i];
}
__device__ __forceinline__ floatx4 max4(floatx4 a, floatx4 b) {
    floatx4 r;
    r[0] = fmaxf(a[0], b[0]); r[1] = fmaxf(a[1], b[1]);
    r[2] = fmaxf(a[2], b[2]); r[3] = fmaxf(a[3], b[3]);
    return r;
}

// ---------- dtype probe: flags[0]=floats-are-bf16, flags[1]=ints-are-int64 ----
__global__ __launch_bounds__(64)
void k_probe(const u16* __restrict__ xu, const int* __restrict__ ei,
             int* __restrict__ flags) {
    int lane = threadIdx.x;
    u16 h = xu[2 * lane];
    u32 E = (h >> 7) & 0xFF;
    int sane = (h == 0) || (E >= 90 && E <= 140);
    unsigned long long m = __ballot(sane);
    int cnt = __popcll(m);
    int z = (lane < 16) ? ei[2 * lane + 1] : 0;
    unsigned long long nz = __ballot(z != 0);
    if (lane == 0) {
        flags[0] = (cnt >= 48) ? 1 : 0;
        flags[1] = (nz == 0ull) ? 1 : 0;
    }
}

__device__ __forceinline__ int ld_row(const int* ei, int e, int is64) {
    return is64 ? ei[2 * (size_t)e] : ei[e];
}
__device__ __forceinline__ int ld_col(const int* ei, int e, int is64) {
    return is64 ? ei[2 * ((size_t)N_EDGES + e)] : ei[(size_t)N_EDGES + e];
}

// ---------- prep: Wt + W1bt bf16 staging + fp32 conversion of small params ---
__global__ __launch_bounds__(256)
void k_prep(const void* __restrict__ WM, const void* __restrict__ WA,
            const void* __restrict__ WS, const void* __restrict__ W1,
            const void* __restrict__ bM, const void* __restrict__ bA,
            const void* __restrict__ b1, const void* __restrict__ W2,
            const void* __restrict__ b2,
            u16* __restrict__ Wt, u16* __restrict__ W1bt,
            float* __restrict__ bMf, float* __restrict__ bAf,
            float* __restrict__ b1f, float* __restrict__ W2f,
            float* __restrict__ b2f, const int* __restrict__ flags) {
    const int isbf = flags[0];
    int t = blockIdx.x * 256 + threadIdx.x;
    if (t < F_CAT * K_PAD) {
        int n = t / K_PAD, k = t - n * K_PAD;
        u16 v = 0;
        if (k < F_IN) {
            const void* W = (n < 48) ? WM : (n < 96) ? WA : WS;
            int nn = (n < 48) ? n : (n < 96) ? n - 48 : n - 96;
            if (isbf) v = ((const u16*)W)[(size_t)k * 48 + nn];
            else      v = f2bf(((const float*)W)[(size_t)k * 48 + nn]);
        }
        Wt[(size_t)n * K_PAD + k] = v;
        return;
    }
    t -= F_CAT * K_PAD;
    if (t < F_MID * K_MLP) {       // W1bt[j][k] = bf16(W1[k][j]), zero-pad k>=144
        int j = t / K_MLP, k = t - j * K_MLP;
        u16 v = 0;
        if (k < F_CAT) {
            if (isbf) v = ((const u16*)W1)[(size_t)k * F_MID + j];
            else      v = f2bf(((const float*)W1)[(size_t)k * F_MID + j]);
        }
        W1bt[t] = v;
        return;
    }
    t -= F_MID * K_MLP;
    if (t < 48)            { bMf[t] = ldf(bM, t, isbf); return; }
    t -= 48;
    if (t < 48)            { bAf[t] = ldf(bA, t, isbf); return; }
    t -= 48;
    if (t < 64)            { b1f[t] = ldf(b1, t, isbf); return; }
    t -= 64;
    if (t < 64)            { W2f[t] = ldf(W2, t, isbf); return; }
    t -= 64;
    if (t < 1)             { b2f[0] = ldf(b2, 0, isbf); return; }
}

// pass 1: per-edge within-(column,replica) rank + replicated column counts.
// R_CNT replicas cut per-address atomic contention 32 -> 2 and per-64B-line
// contention 512 -> 32 (the memory-side atomic serialization that made this
// pass 72us).
__global__ __launch_bounds__(256)
void k_epass1(const int* __restrict__ ei, int* __restrict__ count,
              int* __restrict__ rank, const int* __restrict__ flags) {
    const int is64 = flags[1];
    int e = blockIdx.x * 256 + threadIdx.x;
    if (e >= N_EDGES) return;
    int c = ld_col(ei, e, is64);
    int r = blockIdx.x & (R_CNT - 1);
    rank[e] = atomicAdd(&count[(size_t)r * N_NODES + c], 1);
}

// convert replica counts -> within-column exclusive prefix (in place);
// emit per-column totals for the scan.
__global__ __launch_bounds__(256)
void k_rprefix(int* __restrict__ count, int* __restrict__ coltot) {
    int c = blockIdx.x * 256 + threadIdx.x;
    if (c >= N_NODES) return;
    int tot = 0;
#pragma unroll
    for (int r = 0; r < R_CNT; ++r) {
        int* a = count + (size_t)r * N_NODES + c;
        int v = *a; *a = tot; tot += v;
    }
    coltot[c] = tot;
}

__global__ __launch_bounds__(1024)
void k_scan(const int* __restrict__ coltot, int* __restrict__ rowptr) {
    __shared__ int part[1024];
    const int tid = threadIdx.x;
    const int CH = 52;                 // 1024*52 = 53248 >= 50000, CH%4==0
    int base = tid * CH;
    int s = 0;
#pragma unroll
    for (int i = 0; i < CH / 4; ++i) {
        int idx = base + 4 * i;
        if (idx < N_NODES) {           // N_NODES%4==0 -> full int4 in bounds
            int4 v = *(const int4*)(coltot + idx);
            s += v.x + v.y + v.z + v.w;
        }
    }
    part[tid] = s;
    __syncthreads();
    for (int off = 1; off < 1024; off <<= 1) {
        int v = (tid >= off) ? part[tid - off] : 0;
        __syncthreads();
        part[tid] += v;
        __syncthreads();
    }
    int run = part[tid] - s;           // exclusive prefix of this chunk
#pragma unroll
    for (int i = 0; i < CH / 4; ++i) {
        int idx = base + 4 * i;
        if (idx < N_NODES) {
            int4 v = *(const int4*)(coltot + idx);
            int4 rp;
            rp.x = run; run += v.x;
            rp.y = run; run += v.y;
            rp.z = run; run += v.z;
            rp.w = run; run += v.w;
            *(int4*)(rowptr + idx) = rp;
        }
    }
    if (tid == 1023) rowptr[N_NODES] = part[1023];
}

// pass 2: atomic-free placement — one scattered 8B store per edge (raw w).
// p = rowptr[c] + rbase[r][c] + within-replica rank. rbase (=count after
// k_rprefix) is 3.2MB -> L2/IC resident scattered read.
__global__ __launch_bounds__(256)
void k_epass2(const int* __restrict__ ei, const void* __restrict__ ew,
              const int* __restrict__ rowptr, const int* __restrict__ rank,
              const int* __restrict__ rbase,
              int2* __restrict__ csr_pair, const int* __restrict__ flags) {
    const int isbf = flags[0], is64 = flags[1];
    int e = blockIdx.x * 256 + threadIdx.x;
    if (e >= N_EDGES) return;
    int r = ld_row(ei, e, is64);
    int c = ld_col(ei, e, is64);
    float w = ldf(ew, e, isbf);
    int rep = blockIdx.x & (R_CNT - 1);          // must match k_epass1 mapping
    int p = rowptr[c] + rbase[(size_t)rep * N_NODES + c] + rank[e];
    csr_pair[p] = make_int2(r, __float_as_int(w));
}

// deg/dis from CSR segments, no atomics: one wave per node
__global__ __launch_bounds__(256)
void k_deg(const int* __restrict__ rowptr, const int2* __restrict__ csr_pair,
           float* __restrict__ dis) {
    const int lane = threadIdx.x & 63;
    const int node = blockIdx.x * 4 + (threadIdx.x >> 6);
    int start = rowptr[node], end = rowptr[node + 1];
    float s = 0.f;
    for (int i = start + lane; i < end; i += 64)
        s += __int_as_float(csr_pair[i].y);
#pragma unroll
    for (int off = 32; off > 0; off >>= 1) s += __shfl_down(s, off, 64);
    if (lane == 0) dis[node] = rsqrtf(1.0f + s);   // +1 = self-loop
}

// ---------- GEMM: H[50000 x 144] = x @ [WM|WA|WS] via bf16 MFMA ----------
// hMB[node][96] bf16 (gather table); hFull[node][96..143] = relu(xWS+bS) bf16
__global__ __launch_bounds__(256)
void k_gemm(const void* __restrict__ x, const u16* __restrict__ Wt,
            u16* __restrict__ hMB, u16* __restrict__ hFull,
            const void* __restrict__ bS, const int* __restrict__ flags) {
    const int isbf = flags[0];
    const int lane = threadIdx.x & 63;
    const int wave = threadIdx.x >> 6;
    const int mrow = lane & 15;
    const int q    = lane >> 4;
    const int m_base = blockIdx.x * 128 + wave * 32;

    floatx4 acc[2][9];
#pragma unroll
    for (int tt = 0; tt < 2; ++tt)
#pragma unroll
        for (int t = 0; t < 9; ++t) {
            acc[tt][t][0]=0.f; acc[tt][t][1]=0.f; acc[tt][t][2]=0.f; acc[tt][t][3]=0.f;
        }

    for (int k0 = 0; k0 < K_PAD; k0 += 32) {
        int k = k0 + q * 8;
        short8 a[2];
#pragma unroll
        for (int tt = 0; tt < 2; ++tt) {
            int node = m_base + tt * 16 + mrow;
            short8 av = {0,0,0,0,0,0,0,0};
            if (node < N_NODES && k < F_IN) {
                if (isbf) {
                    av = *(const short8*)((const u16*)x + (size_t)node * F_IN + k);
                } else {
                    const float* xf = (const float*)x + (size_t)node * F_IN + k;
                    floatx4 v0 = *(const floatx4*)xf;
                    floatx4 v1 = *(const floatx4*)(xf + 4);
                    av[0]=(short)f2bf(v0[0]); av[1]=(short)f2bf(v0[1]);
                    av[2]=(short)f2bf(v0[2]); av[3]=(short)f2bf(v0[3]);
                    av[4]=(short)f2bf(v1[0]); av[5]=(short)f2bf(v1[1]);
                    av[6]=(short)f2bf(v1[2]); av[7]=(short)f2bf(v1[3]);
                }
            }
            a[tt] = av;
        }
#pragma unroll
        for (int t = 0; t < 9; ++t) {
            short8 b = *(const short8*)(Wt + (size_t)(t * 16 + mrow) * K_PAD + k);
            acc[0][t] = __builtin_amdgcn_mfma_f32_16x16x32_bf16(a[0], b, acc[0][t], 0, 0, 0);
            acc[1][t] = __builtin_amdgcn_mfma_f32_16x16x32_bf16(a[1], b, acc[1][t], 0, 0, 0);
        }
    }
#pragma unroll
    for (int tt = 0; tt < 2; ++tt)
#pragma unroll
    for (int t = 0; t < 9; ++t) {
        int n = t * 16 + mrow;                      // C/D col = lane&15
#pragma unroll
        for (int r = 0; r < 4; ++r) {
            int row = m_base + tt * 16 + q * 4 + r; // C/D row = (lane>>4)*4 + reg
            if (row < N_NODES) {
                float v = acc[tt][t][r];
                if (n < 96) hMB[(size_t)row * 96 + n] = f2bf(v);
                else        hFull[(size_t)row * F_CAT + n] =
                                f2bf(fmaxf(v + ldf(bS, n - 96, isbf), 0.f));
            }
        }
    }
}

// ---------- aggregation only: one wave per node, writes hFull[.][0..95] ------
// Register-blocked pair prefetch (64 edges per VMEM) + 4x-unrolled gathers.
// No LDS, no syncthreads, no MLP (that moved to k_mlp).
__global__ __launch_bounds__(256)
void k_agg(const u16* __restrict__ hMB, u16* __restrict__ hFull,
           const int* __restrict__ rowptr, const int2* __restrict__ csr_pair,
           const float* __restrict__ dis,
           const float* __restrict__ bMf, const float* __restrict__ bAf) {
    const int lane = threadIdx.x & 63;
    const int wave = threadIdx.x >> 6;
    const int node = blockIdx.x * 4 + wave;   // grid = 12500*4 == 50000 exactly

    const int g = lane / 12;                  // edge group 0..5 (g==5: lanes 60-63 pad)
    const int s = lane - g * 12;              // feature slot 0..11 (8 bf16 each)
    const bool active = lane < 60;
    const bool isMax = s < 6;                 // slots 0..5: hM max, 6..11: hA sum

    const int start = rowptr[node];
    const int end   = rowptr[node + 1];
    const float dn  = dis[node];
    const float dn2 = dn * dn;                // self-loop norm

    // self row (bf16), also reused as the pad row
    const u16* nrow = hMB + (size_t)node * 96 + 8 * s;

    // seed with self-loop contribution.
    // max lanes may seed in every group (idempotent under max); SUM lanes
    // seed only in group 0 (else self-loop counted 5x after combine).
    floatx4 a0, a1;
    {
        short8 rv = *(const short8*)nrow;
        float seed = (isMax || g == 0) ? dn2 : 0.f;
#pragma unroll
        for (int j = 0; j < 4; ++j) {
            a0[j] = seed * bf2f((u16)rv[j]);
            a1[j] = seed * bf2f((u16)rv[4 + j]);
        }
    }

    for (int c0 = start; c0 < end; c0 += 64) {
        int cl = end - c0; if (cl > 64) cl = 64;
        // block-load up to 64 pairs: lane i holds edge c0+i  (clamped, no OOB)
        int li = lane < cl ? lane : cl - 1;
        int2 mp = csr_pair[c0 + li];
        float mynm = __int_as_float(mp.y) * dis[mp.x] * dn;   // full norm

        for (int j = 0; j < cl; j += 20) {
            // stage 1: addresses + weights via shfl (no VMEM dependency)
            const u16* rp[4]; float nmv[4];
#pragma unroll
            for (int u = 0; u < 4; ++u) {
                int el = j + 5 * u + g;
                bool valid = active && (el < cl);
                int elc = (el < cl) ? el : 0;
                int r    = __shfl(mp.x, elc, 64);
                float nm = __shfl(mynm, elc, 64);
                if (!valid) { nm = isMax ? dn2 : 0.f; }
                rp[u]  = valid ? (hMB + (size_t)r * 96 + 8 * s) : nrow;
                nmv[u] = nm;
            }
            // stage 2: 4 independent gathers in flight
            short8 rv[4];
#pragma unroll
            for (int u = 0; u < 4; ++u) rv[u] = *(const short8*)rp[u];
            // stage 3: convert + accumulate
#pragma unroll
            for (int u = 0; u < 4; ++u) {
                floatx4 m0, m1;
#pragma unroll
                for (int jj = 0; jj < 4; ++jj) {
                    m0[jj] = nmv[u] * bf2f((u16)rv[u][jj]);
                    m1[jj] = nmv[u] * bf2f((u16)rv[u][4 + jj]);
                }
                if (isMax) { a0 = max4(a0, m0); a1 = max4(a1, m1); }
                else       { a0 += m0;          a1 += m1; }
            }
        }
    }

    // combine the 5 groups into lanes 0..11
#pragma unroll
    for (int gg = 1; gg < 5; ++gg) {
        int src = lane + 12 * gg;
        floatx4 t0, t1;
#pragma unroll
        for (int j = 0; j < 4; ++j) {
            t0[j] = __shfl(a0[j], src, 64);
            t1[j] = __shfl(a1[j], src, 64);
        }
        if (lane < 12) {
            if (isMax) { a0 = max4(a0, t0); a1 = max4(a1, t1); }
            else       { a0 += t0;          a1 += t1; }
        }
    }

    if (lane < 12) {
        const float* bp = isMax ? (bMf + 8 * lane) : (bAf + 8 * lane - 48);
        short8 hv;
#pragma unroll
        for (int j = 0; j < 4; ++j) {
            hv[j]     = (short)f2bf(fmaxf(a0[j] + bp[j],     0.f));
            hv[4 + j] = (short)f2bf(fmaxf(a1[j] + bp[4 + j], 0.f));
        }
        *(short8*)(hFull + (size_t)node * F_CAT + 8 * lane) = hv;
    }
}

// ---------- MLP via MFMA: out = (relu(hFull@W1+b1))@W2 + b2 ----------------
// M=50000, K=144 (pad 160), N=64; fused ReLU + W2 dot + b2 in epilogue.
__global__ __launch_bounds__(256)
void k_mlp(const u16* __restrict__ hFull, const u16* __restrict__ W1bt,
           const float* __restrict__ b1f, const float* __restrict__ W2f,
           const float* __restrict__ b2f, void* __restrict__ out,
           const int* __restrict__ flags) {
    const int isbf = flags[0];
    const int lane = threadIdx.x & 63;
    const int wave = threadIdx.x >> 6;
    const int mrow = lane & 15;
    const int q    = lane >> 4;
    const int m_base = blockIdx.x * 64 + wave * 16;
    const int node = m_base + mrow;           // A-operand row

    floatx4 acc[4];
#pragma unroll
    for (int t = 0; t < 4; ++t) { acc[t][0]=0.f; acc[t][1]=0.f; acc[t][2]=0.f; acc[t][3]=0.f; }

    for (int k0 = 0; k0 < K_MLP; k0 += 32) {
        int k = k0 + q * 8;
        short8 a = {0,0,0,0,0,0,0,0};
        if (node < N_NODES && k < F_CAT)
            a = *(const short8*)(hFull + (size_t)node * F_CAT + k);
#pragma unroll
        for (int t = 0; t < 4; ++t) {
            short8 b = *(const short8*)(W1bt + (size_t)(t * 16 + mrow) * K_MLP + k);
            acc[t] = __builtin_amdgcn_mfma_f32_16x16x32_bf16(a, b, acc[t], 0, 0, 0);
        }
    }

    // epilogue: per lane col c=mrow holds mid[n=t*16+c] for rows m=q*4+r
    float pr[4] = {0.f, 0.f, 0.f, 0.f};
#pragma unroll
    for (int t = 0; t < 4; ++t) {
        int n = t * 16 + mrow;
        float b1v = b1f[n], w2v = W2f[n];
#pragma unroll
        for (int r = 0; r < 4; ++r)
            pr[r] += fmaxf(acc[t][r] + b1v, 0.f) * w2v;
    }
    // reduce across the 16 columns (lanes with equal q)
#pragma unroll
    for (int mask = 1; mask < 16; mask <<= 1)
#pragma unroll
        for (int r = 0; r < 4; ++r) pr[r] += __shfl_xor(pr[r], mask, 64);
    if (mrow == 0) {
#pragma unroll
        for (int r = 0; r < 4; ++r) {
            int nd = m_base + q * 4 + r;
            if (nd < N_NODES) {
                float res = pr[r] + b2f[0];
                if (isbf) ((u16*)out)[nd] = f2bf(res);
                else      ((float*)out)[nd] = res;
            }
        }
    }
}

extern "C" void kernel_launch(void* const* d_in, const int* in_sizes, int n_in,
                              void* d_out, int out_size, void* d_ws, size_t ws_size,
                              hipStream_t stream) {
    const void* x  = d_in[0];
    const int*  ei = (const int*)d_in[1];
    const void* ew = d_in[2];
    const void* WM = d_in[3];
    const void* bM = d_in[4];
    const void* WA = d_in[5];
    const void* bA = d_in[6];
    const void* WS = d_in[7];
    const void* bS = d_in[8];
    const void* W1 = d_in[9];
    const void* b1 = d_in[10];
    const void* W2 = d_in[11];
    const void* b2 = d_in[12];

    char* p = (char*)d_ws;
    auto alloc = [&](size_t bytes) -> char* {
        char* r = p; p += (bytes + 255) & ~(size_t)255; return r;
    };
    int*   flags    = (int*)  alloc(16);
    float* dis      = (float*)alloc((size_t)N_NODES * 4);
    int*   count    = (int*)  alloc((size_t)R_CNT * N_NODES * 4);
    int*   rowptr   = (int*)  alloc((size_t)(N_NODES + 1) * 4);
    int*   rank     = (int*)  alloc((size_t)N_EDGES * 4);
    int2*  csr_pair = (int2*) alloc((size_t)N_EDGES * 8);
    u16*   hMB      = (u16*)  alloc((size_t)N_NODES * 96 * 2);
    u16*   hFull    = (u16*)  alloc((size_t)N_NODES * F_CAT * 2);
    u16*   Wt       = (u16*)  alloc((size_t)F_CAT * K_PAD * 2);
    u16*   W1bt    = (u16*)  alloc((size_t)F_MID * K_MLP * 2);
    float* bMf      = (float*)alloc(48 * 4);
    float* bAf      = (float*)alloc(48 * 4);
    float* b1f      = (float*)alloc(64 * 4);
    float* W2f      = (float*)alloc(64 * 4);
    float* b2f      = (float*)alloc(4);
    // coltot aliases dis: k_rprefix writes + k_scan reads it strictly before
    // k_deg writes dis. Saves workspace.
    int*   coltot   = (int*)dis;

    k_probe <<<1, 64, 0, stream>>>((const u16*)x, ei, flags);
    k_prep  <<<(F_CAT * K_PAD + F_MID * K_MLP + 225 + 255) / 256, 256, 0, stream>>>(
                 WM, WA, WS, W1, bM, bA, b1, W2, b2,
                 Wt, W1bt, bMf, bAf, b1f, W2f, b2f, flags);
    hipMemsetAsync(count, 0, (size_t)R_CNT * N_NODES * 4, stream);
    k_epass1<<<(N_EDGES + 255) / 256, 256, 0, stream>>>(ei, count, rank, flags);
    k_rprefix<<<(N_NODES + 255) / 256, 256, 0, stream>>>(count, coltot);
    k_scan  <<<1, 1024, 0, stream>>>(coltot, rowptr);
    k_epass2<<<(N_EDGES + 255) / 256, 256, 0, stream>>>(ei, ew, rowptr, rank, count, csr_pair, flags);
    k_deg   <<<(N_NODES + 3) / 4, 256, 0, stream>>>(rowptr, csr_pair, dis);
    k_gemm  <<<(N_NODES + 127) / 128, 256, 0, stream>>>(x, Wt, hMB, hFull, bS, flags);
    k_agg   <<<N_NODES / 4, 256, 0, stream>>>(hMB, hFull, rowptr, csr_pair, dis, bMf, bAf);
    k_mlp   <<<(N_NODES + 63) / 64, 256, 0, stream>>>(hFull, W1bt, b1f, W2f, b2f, d_out, flags);
    (void)in_sizes; (void)n_in; (void)out_size; (void)ws_size;
}

// Round 3
// 338.827 us; speedup vs baseline: 1.0272x; 1.0170x over previous
//
#include <hip/hip_runtime.h>
#include <stdint.h>

#define N_NODES 50000
#define N_EDGES 1600000
#define F_IN    264
#define F_HID   48
#define F_CAT   144
#define F_MID   64
#define K_PAD   288   // 264 padded up to multiple of 32
#define K_MLP   160   // 144 padded up to multiple of 32
#define R_CNT   16    // count-array replication factor (atomic contention fix)

typedef unsigned short u16;
typedef unsigned int   u32;

using short8  = __attribute__((ext_vector_type(8))) short;
using floatx4 = __attribute__((ext_vector_type(4))) float;
using floatx2 = __attribute__((ext_vector_type(2))) float;
using uintx4  = __attribute__((ext_vector_type(4))) u32;

__device__ __forceinline__ float bf2f(u16 u) {
    return __uint_as_float(((u32)u) << 16);
}
__device__ __forceinline__ u16 f2bf(float f) {
    u32 u = __float_as_uint(f);
    u32 r = (u + 0x7fffu + ((u >> 16) & 1u)) >> 16;   // round-nearest-even
    return (u16)r;
}
// dtype-agnostic scalar float load: isbf ? bf16[i] : f32[i]
__device__ __forceinline__ float ldf(const void* p, size_t i, int isbf) {
    return isbf ? bf2f(((const u16*)p)[i]) : ((const float*)p)[i];
}
__device__ __forceinline__ uintx4 s8_to_u4(short8 v) {
    union { short8 s; uintx4 u; } c; c.s = v; return c.u;
}

// ---------- dtype probe: flags[0]=floats-are-bf16, flags[1]=ints-are-int64 ----
__global__ __launch_bounds__(64)
void k_probe(const u16* __restrict__ xu, const int* __restrict__ ei,
             int* __restrict__ flags) {
    int lane = threadIdx.x;
    u16 h = xu[2 * lane];
    u32 E = (h >> 7) & 0xFF;
    int sane = (h == 0) || (E >= 90 && E <= 140);
    unsigned long long m = __ballot(sane);
    int cnt = __popcll(m);
    int z = (lane < 16) ? ei[2 * lane + 1] : 0;
    unsigned long long nz = __ballot(z != 0);
    if (lane == 0) {
        flags[0] = (cnt >= 48) ? 1 : 0;
        flags[1] = (nz == 0ull) ? 1 : 0;
    }
}

__device__ __forceinline__ int ld_row(const int* ei, int e, int is64) {
    return is64 ? ei[2 * (size_t)e] : ei[e];
}
__device__ __forceinline__ int ld_col(const int* ei, int e, int is64) {
    return is64 ? ei[2 * ((size_t)N_EDGES + e)] : ei[(size_t)N_EDGES + e];
}

// ---------- prep: Wt + W1bt bf16 staging + fp32 conversion of small params ---
__global__ __launch_bounds__(256)
void k_prep(const void* __restrict__ WM, const void* __restrict__ WA,
            const void* __restrict__ WS, const void* __restrict__ W1,
            const void* __restrict__ bM, const void* __restrict__ bA,
            const void* __restrict__ b1, const void* __restrict__ W2,
            const void* __restrict__ b2,
            u16* __restrict__ Wt, u16* __restrict__ W1bt,
            float* __restrict__ bMf, float* __restrict__ bAf,
            float* __restrict__ b1f, float* __restrict__ W2f,
            float* __restrict__ b2f, const int* __restrict__ flags) {
    const int isbf = flags[0];
    int t = blockIdx.x * 256 + threadIdx.x;
    if (t < F_CAT * K_PAD) {
        int n = t / K_PAD, k = t - n * K_PAD;
        u16 v = 0;
        if (k < F_IN) {
            const void* W = (n < 48) ? WM : (n < 96) ? WA : WS;
            int nn = (n < 48) ? n : (n < 96) ? n - 48 : n - 96;
            if (isbf) v = ((const u16*)W)[(size_t)k * 48 + nn];
            else      v = f2bf(((const float*)W)[(size_t)k * 48 + nn]);
        }
        Wt[(size_t)n * K_PAD + k] = v;
        return;
    }
    t -= F_CAT * K_PAD;
    if (t < F_MID * K_MLP) {       // W1bt[j][k] = bf16(W1[k][j]), zero-pad k>=144
        int j = t / K_MLP, k = t - j * K_MLP;
        u16 v = 0;
        if (k < F_CAT) {
            if (isbf) v = ((const u16*)W1)[(size_t)k * F_MID + j];
            else      v = f2bf(((const float*)W1)[(size_t)k * F_MID + j]);
        }
        W1bt[t] = v;
        return;
    }
    t -= F_MID * K_MLP;
    if (t < 48)            { bMf[t] = ldf(bM, t, isbf); return; }
    t -= 48;
    if (t < 48)            { bAf[t] = ldf(bA, t, isbf); return; }
    t -= 48;
    if (t < 64)            { b1f[t] = ldf(b1, t, isbf); return; }
    t -= 64;
    if (t < 64)            { W2f[t] = ldf(W2, t, isbf); return; }
    t -= 64;
    if (t < 1)             { b2f[0] = ldf(b2, 0, isbf); return; }
}

// pass 1: per-edge within-(column,replica) rank + replicated column counts.
// R_CNT replicas cut per-address atomic contention and per-64B-line
// contention (memory-side atomic serialization).
__global__ __launch_bounds__(256)
void k_epass1(const int* __restrict__ ei, int* __restrict__ count,
              int* __restrict__ rank, const int* __restrict__ flags) {
    const int is64 = flags[1];
    int e = blockIdx.x * 256 + threadIdx.x;
    if (e >= N_EDGES) return;
    int c = ld_col(ei, e, is64);
    int r = blockIdx.x & (R_CNT - 1);
    rank[e] = atomicAdd(&count[(size_t)r * N_NODES + c], 1);
}

// convert replica counts -> within-column exclusive prefix (in place);
// emit per-column totals for the scan.
__global__ __launch_bounds__(256)
void k_rprefix(int* __restrict__ count, int* __restrict__ coltot) {
    int c = blockIdx.x * 256 + threadIdx.x;
    if (c >= N_NODES) return;
    int tot = 0;
#pragma unroll
    for (int r = 0; r < R_CNT; ++r) {
        int* a = count + (size_t)r * N_NODES + c;
        int v = *a; *a = tot; tot += v;
    }
    coltot[c] = tot;
}

__global__ __launch_bounds__(1024)
void k_scan(const int* __restrict__ coltot, int* __restrict__ rowptr) {
    __shared__ int part[1024];
    const int tid = threadIdx.x;
    const int CH = 52;                 // 1024*52 = 53248 >= 50000, CH%4==0
    int base = tid * CH;
    int s = 0;
#pragma unroll
    for (int i = 0; i < CH / 4; ++i) {
        int idx = base + 4 * i;
        if (idx < N_NODES) {           // N_NODES%4==0 -> full int4 in bounds
            int4 v = *(const int4*)(coltot + idx);
            s += v.x + v.y + v.z + v.w;
        }
    }
    part[tid] = s;
    __syncthreads();
    for (int off = 1; off < 1024; off <<= 1) {
        int v = (tid >= off) ? part[tid - off] : 0;
        __syncthreads();
        part[tid] += v;
        __syncthreads();
    }
    int run = part[tid] - s;           // exclusive prefix of this chunk
#pragma unroll
    for (int i = 0; i < CH / 4; ++i) {
        int idx = base + 4 * i;
        if (idx < N_NODES) {
            int4 v = *(const int4*)(coltot + idx);
            int4 rp;
            rp.x = run; run += v.x;
            rp.y = run; run += v.y;
            rp.z = run; run += v.z;
            rp.w = run; run += v.w;
            *(int4*)(rowptr + idx) = rp;
        }
    }
    if (tid == 1023) rowptr[N_NODES] = part[1023];
}

// pass 2: atomic-free placement — one scattered 8B store per edge (raw w).
__global__ __launch_bounds__(256)
void k_epass2(const int* __restrict__ ei, const void* __restrict__ ew,
              const int* __restrict__ rowptr, const int* __restrict__ rank,
              const int* __restrict__ rbase,
              int2* __restrict__ csr_pair, const int* __restrict__ flags) {
    const int isbf = flags[0], is64 = flags[1];
    int e = blockIdx.x * 256 + threadIdx.x;
    if (e >= N_EDGES) return;
    int r = ld_row(ei, e, is64);
    int c = ld_col(ei, e, is64);
    float w = ldf(ew, e, isbf);
    int rep = blockIdx.x & (R_CNT - 1);          // must match k_epass1 mapping
    int rb = rbase[(size_t)rep * N_NODES + c];
    int p = rowptr[c] + rb + rank[e];
    csr_pair[p] = make_int2(r, __float_as_int(w));
}

// deg/dis from CSR segments, no atomics: one wave per node
__global__ __launch_bounds__(256)
void k_deg(const int* __restrict__ rowptr, const int2* __restrict__ csr_pair,
           float* __restrict__ dis) {
    const int lane = threadIdx.x & 63;
    const int node = blockIdx.x * 4 + (threadIdx.x >> 6);
    int start = rowptr[node], end = rowptr[node + 1];
    float s = 0.f;
    for (int i = start + lane; i < end; i += 64)
        s += __int_as_float(csr_pair[i].y);
#pragma unroll
    for (int off = 32; off > 0; off >>= 1) s += __shfl_down(s, off, 64);
    if (lane == 0) dis[node] = rsqrtf(1.0f + s);   // +1 = self-loop
}

// ---------- GEMM: H[50000 x 144] = x @ [WM|WA|WS] via bf16 MFMA ----------
// hMB[node][96] bf16 (gather table); hFull[node][96..143] = relu(xWS+bS) bf16
__global__ __launch_bounds__(256)
void k_gemm(const void* __restrict__ x, const u16* __restrict__ Wt,
            u16* __restrict__ hMB, u16* __restrict__ hFull,
            const void* __restrict__ bS, const int* __restrict__ flags) {
    const int isbf = flags[0];
    const int lane = threadIdx.x & 63;
    const int wave = threadIdx.x >> 6;
    const int mrow = lane & 15;
    const int q    = lane >> 4;
    const int m_base = blockIdx.x * 128 + wave * 32;

    floatx4 acc[2][9];
#pragma unroll
    for (int tt = 0; tt < 2; ++tt)
#pragma unroll
        for (int t = 0; t < 9; ++t) {
            acc[tt][t][0]=0.f; acc[tt][t][1]=0.f; acc[tt][t][2]=0.f; acc[tt][t][3]=0.f;
        }

    for (int k0 = 0; k0 < K_PAD; k0 += 32) {
        int k = k0 + q * 8;
        short8 a[2];
#pragma unroll
        for (int tt = 0; tt < 2; ++tt) {
            int node = m_base + tt * 16 + mrow;
            short8 av = {0,0,0,0,0,0,0,0};
            if (node < N_NODES && k < F_IN) {
                if (isbf) {
                    av = *(const short8*)((const u16*)x + (size_t)node * F_IN + k);
                } else {
                    const float* xf = (const float*)x + (size_t)node * F_IN + k;
                    floatx4 v0 = *(const floatx4*)xf;
                    floatx4 v1 = *(const floatx4*)(xf + 4);
                    av[0]=(short)f2bf(v0[0]); av[1]=(short)f2bf(v0[1]);
                    av[2]=(short)f2bf(v0[2]); av[3]=(short)f2bf(v0[3]);
                    av[4]=(short)f2bf(v1[0]); av[5]=(short)f2bf(v1[1]);
                    av[6]=(short)f2bf(v1[2]); av[7]=(short)f2bf(v1[3]);
                }
            }
            a[tt] = av;
        }
#pragma unroll
        for (int t = 0; t < 9; ++t) {
            short8 b = *(const short8*)(Wt + (size_t)(t * 16 + mrow) * K_PAD + k);
            acc[0][t] = __builtin_amdgcn_mfma_f32_16x16x32_bf16(a[0], b, acc[0][t], 0, 0, 0);
            acc[1][t] = __builtin_amdgcn_mfma_f32_16x16x32_bf16(a[1], b, acc[1][t], 0, 0, 0);
        }
    }
#pragma unroll
    for (int tt = 0; tt < 2; ++tt)
#pragma unroll
    for (int t = 0; t < 9; ++t) {
        int n = t * 16 + mrow;                      // C/D col = lane&15
#pragma unroll
        for (int r = 0; r < 4; ++r) {
            int row = m_base + tt * 16 + q * 4 + r; // C/D row = (lane>>4)*4 + reg
            if (row < N_NODES) {
                float v = acc[tt][t][r];
                if (n < 96) hMB[(size_t)row * 96 + n] = f2bf(v);
                else        hFull[(size_t)row * F_CAT + n] =
                                f2bf(fmaxf(v + ldf(bS, n - 96, isbf), 0.f));
            }
        }
    }
}

// ---------- aggregation only: one wave per node, writes hFull[.][0..95] ------
// VALU-slimmed: u32 offsets (umul24 at block-load, shfl'd), packed
// bf16->f32 bit-trick conversion, float2 accumulators for v_pk_fma/mul_f32.
__global__ __launch_bounds__(256)
void k_agg(const u16* __restrict__ hMB, u16* __restrict__ hFull,
           const int* __restrict__ rowptr, const int2* __restrict__ csr_pair,
           const float* __restrict__ dis,
           const float* __restrict__ bMf, const float* __restrict__ bAf) {
    const int lane = threadIdx.x & 63;
    const int wave = threadIdx.x >> 6;
    const int node = blockIdx.x * 4 + wave;   // grid = 12500*4 == 50000 exactly

    const int g = lane / 12;                  // edge group 0..5 (g==5: lanes 60-63 pad)
    const int s = lane - g * 12;              // feature slot 0..11 (8 bf16 each)
    const bool active = lane < 60;
    const bool isMax = s < 6;                 // slots 0..5: hM max, 6..11: hA sum

    const int start = rowptr[node];
    const int end   = rowptr[node + 1];
    const float dn  = dis[node];
    const float dn2 = dn * dn;                // self-loop norm
    const float padnm = isMax ? dn2 : 0.f;    // pad-gather norm (loop-invariant)

    const u32 s16     = 16u * (u32)s;
    const u32 selfOff = __umul24((u32)node, 192u) + s16;   // self/pad row bytes

    // acc2[p] = features {2p, 2p+1} of this lane's 8-feature slot
    floatx2 acc2[4];
    {
        short8 rv0 = *(const short8*)((const char*)hMB + selfOff);
        uintx4 w4 = s8_to_u4(rv0);
        // max lanes may seed in every group (idempotent under max); SUM lanes
        // seed only in group 0 (else self-loop counted 5x after combine).
        float seed = (isMax || g == 0) ? dn2 : 0.f;
#pragma unroll
        for (int p = 0; p < 4; ++p) {
            acc2[p][0] = seed * __uint_as_float(w4[p] << 16);
            acc2[p][1] = seed * __uint_as_float(w4[p] & 0xffff0000u);
        }
    }

    for (int c0 = start; c0 < end; c0 += 64) {
        int cl = end - c0; if (cl > 64) cl = 64;
        // block-load up to 64 pairs: lane i holds edge c0+i  (clamped, no OOB)
        int li = lane < cl ? lane : cl - 1;
        int2 mp = csr_pair[c0 + li];
        float disr = dis[mp.x];
        float mynm = __int_as_float(mp.y) * disr * dn;     // full norm
        u32 myoff  = __umul24((u32)mp.x, 192u);            // row byte offset

        for (int j = 0; j < cl; j += 20) {
            // stage 1: u32 offsets + weights via shfl (no VMEM dependency)
            u32 offv[4]; float nmv[4];
#pragma unroll
            for (int u = 0; u < 4; ++u) {
                int el = j + 5 * u + g;
                bool valid = active && (el < cl);
                int elc = (el < cl) ? el : 0;
                u32 off  = (u32)__shfl((int)myoff, elc, 64) + s16;
                float nm = __shfl(mynm, elc, 64);
                offv[u] = valid ? off : selfOff;
                nmv[u]  = valid ? nm  : padnm;
            }
            // stage 2: 4 independent gathers in flight
            short8 rv[4];
#pragma unroll
            for (int u = 0; u < 4; ++u)
                rv[u] = *(const short8*)((const char*)hMB + offv[u]);
            // stage 3: packed convert + accumulate
#pragma unroll
            for (int u = 0; u < 4; ++u) {
                uintx4 w4 = s8_to_u4(rv[u]);
                floatx2 nm2; nm2[0] = nmv[u]; nm2[1] = nmv[u];
#pragma unroll
                for (int p = 0; p < 4; ++p) {
                    floatx2 f;
                    f[0] = __uint_as_float(w4[p] << 16);
                    f[1] = __uint_as_float(w4[p] & 0xffff0000u);
                    if (isMax) {
                        floatx2 m = nm2 * f;               // v_pk_mul_f32
                        acc2[p][0] = fmaxf(acc2[p][0], m[0]);
                        acc2[p][1] = fmaxf(acc2[p][1], m[1]);
                    } else {
                        acc2[p] += nm2 * f;                // v_pk_fma_f32
                    }
                }
            }
        }
    }

    // combine the 5 groups into lanes 0..11
#pragma unroll
    for (int gg = 1; gg < 5; ++gg) {
        int src = lane + 12 * gg;
        floatx2 t[4];
#pragma unroll
        for (int p = 0; p < 4; ++p) {
            t[p][0] = __shfl(acc2[p][0], src, 64);
            t[p][1] = __shfl(acc2[p][1], src, 64);
        }
        if (lane < 12) {
            if (isMax) {
#pragma unroll
                for (int p = 0; p < 4; ++p) {
                    acc2[p][0] = fmaxf(acc2[p][0], t[p][0]);
                    acc2[p][1] = fmaxf(acc2[p][1], t[p][1]);
                }
            } else {
#pragma unroll
                for (int p = 0; p < 4; ++p) acc2[p] += t[p];
            }
        }
    }

    if (lane < 12) {
        const float* bp = isMax ? (bMf + 8 * lane) : (bAf + 8 * lane - 48);
        short8 hv;
#pragma unroll
        for (int p = 0; p < 4; ++p) {
            hv[2 * p]     = (short)f2bf(fmaxf(acc2[p][0] + bp[2 * p],     0.f));
            hv[2 * p + 1] = (short)f2bf(fmaxf(acc2[p][1] + bp[2 * p + 1], 0.f));
        }
        *(short8*)(hFull + (size_t)node * F_CAT + 8 * lane) = hv;
    }
}

// ---------- MLP via MFMA: out = (relu(hFull@W1+b1))@W2 + b2 ----------------
// M=50000, K=144 (pad 160), N=64; fused ReLU + W2 dot + b2 in epilogue.
__global__ __launch_bounds__(256)
void k_mlp(const u16* __restrict__ hFull, const u16* __restrict__ W1bt,
           const float* __restrict__ b1f, const float* __restrict__ W2f,
           const float* __restrict__ b2f, void* __restrict__ out,
           const int* __restrict__ flags) {
    const int isbf = flags[0];
    const int lane = threadIdx.x & 63;
    const int wave = threadIdx.x >> 6;
    const int mrow = lane & 15;
    const int q    = lane >> 4;
    const int m_base = blockIdx.x * 64 + wave * 16;
    const int node = m_base + mrow;           // A-operand row

    floatx4 acc[4];
#pragma unroll
    for (int t = 0; t < 4; ++t) { acc[t][0]=0.f; acc[t][1]=0.f; acc[t][2]=0.f; acc[t][3]=0.f; }

    for (int k0 = 0; k0 < K_MLP; k0 += 32) {
        int k = k0 + q * 8;
        short8 a = {0,0,0,0,0,0,0,0};
        if (node < N_NODES && k < F_CAT)
            a = *(const short8*)(hFull + (size_t)node * F_CAT + k);
#pragma unroll
        for (int t = 0; t < 4; ++t) {
            short8 b = *(const short8*)(W1bt + (size_t)(t * 16 + mrow) * K_MLP + k);
            acc[t] = __builtin_amdgcn_mfma_f32_16x16x32_bf16(a, b, acc[t], 0, 0, 0);
        }
    }

    // epilogue: per lane col c=mrow holds mid[n=t*16+c] for rows m=q*4+r
    float pr[4] = {0.f, 0.f, 0.f, 0.f};
#pragma unroll
    for (int t = 0; t < 4; ++t) {
        int n = t * 16 + mrow;
        float b1v = b1f[n], w2v = W2f[n];
#pragma unroll
        for (int r = 0; r < 4; ++r)
            pr[r] += fmaxf(acc[t][r] + b1v, 0.f) * w2v;
    }
    // reduce across the 16 columns (lanes with equal q)
#pragma unroll
    for (int mask = 1; mask < 16; mask <<= 1)
#pragma unroll
        for (int r = 0; r < 4; ++r) pr[r] += __shfl_xor(pr[r], mask, 64);
    if (mrow == 0) {
#pragma unroll
        for (int r = 0; r < 4; ++r) {
            int nd = m_base + q * 4 + r;
            if (nd < N_NODES) {
                float res = pr[r] + b2f[0];
                if (isbf) ((u16*)out)[nd] = f2bf(res);
                else      ((float*)out)[nd] = res;
            }
        }
    }
}

extern "C" void kernel_launch(void* const* d_in, const int* in_sizes, int n_in,
                              void* d_out, int out_size, void* d_ws, size_t ws_size,
                              hipStream_t stream) {
    const void* x  = d_in[0];
    const int*  ei = (const int*)d_in[1];
    const void* ew = d_in[2];
    const void* WM = d_in[3];
    const void* bM = d_in[4];
    const void* WA = d_in[5];
    const void* bA = d_in[6];
    const void* WS = d_in[7];
    const void* bS = d_in[8];
    const void* W1 = d_in[9];
    const void* b1 = d_in[10];
    const void* W2 = d_in[11];
    const void* b2 = d_in[12];

    char* p = (char*)d_ws;
    auto alloc = [&](size_t bytes) -> char* {
        char* r = p; p += (bytes + 255) & ~(size_t)255; return r;
    };
    int*   flags    = (int*)  alloc(16);
    float* dis      = (float*)alloc((size_t)N_NODES * 4);
    int*   count    = (int*)  alloc((size_t)R_CNT * N_NODES * 4);
    int*   rowptr   = (int*)  alloc((size_t)(N_NODES + 1) * 4);
    int*   rank     = (int*)  alloc((size_t)N_EDGES * 4);
    int2*  csr_pair = (int2*) alloc((size_t)N_EDGES * 8);
    u16*   hMB      = (u16*)  alloc((size_t)N_NODES * 96 * 2);
    u16*   hFull    = (u16*)  alloc((size_t)N_NODES * F_CAT * 2);
    u16*   Wt       = (u16*)  alloc((size_t)F_CAT * K_PAD * 2);
    u16*   W1bt    = (u16*)  alloc((size_t)F_MID * K_MLP * 2);
    float* bMf      = (float*)alloc(48 * 4);
    float* bAf      = (float*)alloc(48 * 4);
    float* b1f      = (float*)alloc(64 * 4);
    float* W2f      = (float*)alloc(64 * 4);
    float* b2f      = (float*)alloc(4);
    // coltot aliases dis: k_rprefix writes + k_scan reads it strictly before
    // k_deg writes dis. Saves workspace.
    int*   coltot   = (int*)dis;

    k_probe <<<1, 64, 0, stream>>>((const u16*)x, ei, flags);
    k_prep  <<<(F_CAT * K_PAD + F_MID * K_MLP + 225 + 255) / 256, 256, 0, stream>>>(
                 WM, WA, WS, W1, bM, bA, b1, W2, b2,
                 Wt, W1bt, bMf, bAf, b1f, W2f, b2f, flags);
    hipMemsetAsync(count, 0, (size_t)R_CNT * N_NODES * 4, stream);
    k_epass1<<<(N_EDGES + 255) / 256, 256, 0, stream>>>(ei, count, rank, flags);
    k_rprefix<<<(N_NODES + 255) / 256, 256, 0, stream>>>(count, coltot);
    k_scan  <<<1, 1024, 0, stream>>>(coltot, rowptr);
    k_epass2<<<(N_EDGES + 255) / 256, 256, 0, stream>>>(ei, ew, rowptr, rank, count, csr_pair, flags);
    k_deg   <<<(N_NODES + 3) / 4, 256, 0, stream>>>(rowptr, csr_pair, dis);
    k_gemm  <<<(N_NODES + 127) / 128, 256, 0, stream>>>(x, Wt, hMB, hFull, bS, flags);
    k_agg   <<<N_NODES / 4, 256, 0, stream>>>(hMB, hFull, rowptr, csr_pair, dis, bMf, bAf);
    k_mlp   <<<(N_NODES + 63) / 64, 256, 0, stream>>>(hFull, W1bt, b1f, W2f, b2f, d_out, flags);
    (void)in_sizes; (void)n_in; (void)out_size; (void)ws_size;
}